// Round 5
// baseline (247.264 us; speedup 1.0000x reference)
//
#include <hip/hip_runtime.h>
#include <hip/hip_bf16.h>
#include <cstdint>
#include <cstddef>

// Problem constants
#define B_DIM   8192
#define OBS_DIM 256
#define ACT_DIM 32
#define HID_DIM 512
#define NEXPERT 8

typedef __attribute__((ext_vector_type(4))) float        f32x4;
typedef __attribute__((ext_vector_type(8))) short        s16x8;   // 8 bf16 in 4 VGPRs
typedef __attribute__((ext_vector_type(4))) unsigned int u32x4;

// v_cvt_pk_bf16_f32: D[15:0]=bf16(lo), D[31:16]=bf16(hi), RNE. No builtin on gfx950.
__device__ __forceinline__ unsigned cvt_pk_bf16(float lo, float hi) {
    unsigned r;
    asm("v_cvt_pk_bf16_f32 %0, %1, %2" : "=v"(r) : "v"(lo), "v"(hi));
    return r;
}
__device__ __forceinline__ float bf16_lo_f32(unsigned u) { return __uint_as_float(u << 16); }
__device__ __forceinline__ float bf16_hi_f32(unsigned u) { return __uint_as_float(u & 0xffff0000u); }

// ---------------------------------------------------------------------------
// fp32 -> bf16 bulk convert, 7 segments, block-partitioned.
// ---------------------------------------------------------------------------
struct CvtArgs {
    const float*    s[7];
    unsigned short* d[7];
    int             nb[7];
};

__global__ __launch_bounds__(256) void cvt_multi(CvtArgs a) {
    int bid = blockIdx.x;
    int seg = 0, base = 0;
    while (seg < 6 && bid >= base + a.nb[seg]) { base += a.nb[seg]; ++seg; }
    int local = (bid - base) * 256 + threadIdx.x;
    const f32x4* s = (const f32x4*)a.s[seg];
    f32x4 v0 = s[local * 2 + 0];
    f32x4 v1 = s[local * 2 + 1];
    u32x4 o;
    o[0] = cvt_pk_bf16(v0[0], v0[1]);
    o[1] = cvt_pk_bf16(v0[2], v0[3]);
    o[2] = cvt_pk_bf16(v1[0], v1[1]);
    o[3] = cvt_pk_bf16(v1[2], v1[3]);
    ((u32x4*)a.d[seg])[local] = o;
}

// ---------------------------------------------------------------------------
// Gate head: logits = h1 @ gw2.T + gb2 ; blend = softmax(logits). One wave/row.
// ---------------------------------------------------------------------------
__global__ __launch_bounds__(256) void gate_softmax(const unsigned short* __restrict__ h1,
                                                    const unsigned short* __restrict__ gw2,
                                                    const float* __restrict__ gb2,
                                                    float* __restrict__ blend) {
    const int lane = threadIdx.x & 63;
    const int wid  = threadIdx.x >> 6;
    const int row  = blockIdx.x * 4 + wid;

    u32x4 xv = *(const u32x4*)(h1 + (size_t)row * HID_DIM + lane * 8);
    float x[8];
#pragma unroll
    for (int j = 0; j < 4; ++j) {
        unsigned u   = xv[j];
        x[2 * j]     = bf16_lo_f32(u);
        x[2 * j + 1] = bf16_hi_f32(u);
    }
    float s[NEXPERT];
#pragma unroll
    for (int pp = 0; pp < NEXPERT; ++pp) {
        u32x4 wv = *(const u32x4*)(gw2 + (size_t)pp * HID_DIM + lane * 8);
        float d  = 0.f;
#pragma unroll
        for (int j = 0; j < 4; ++j) {
            unsigned u = wv[j];
            d += x[2 * j] * bf16_lo_f32(u);
            d += x[2 * j + 1] * bf16_hi_f32(u);
        }
        s[pp] = d;
    }
#pragma unroll
    for (int off = 1; off < 64; off <<= 1) {
#pragma unroll
        for (int pp = 0; pp < NEXPERT; ++pp) s[pp] += __shfl_xor(s[pp], off);
    }
    if (lane == 0) {
        float l[NEXPERT], m = -1e30f;
#pragma unroll
        for (int pp = 0; pp < NEXPERT; ++pp) { l[pp] = s[pp] + gb2[pp]; m = fmaxf(m, l[pp]); }
        float sum = 0.f;
#pragma unroll
        for (int pp = 0; pp < NEXPERT; ++pp) { l[pp] = __expf(l[pp] - m); sum += l[pp]; }
        float inv = 1.f / sum;
#pragma unroll
        for (int pp = 0; pp < NEXPERT; ++pp) blend[(size_t)row * NEXPERT + pp] = l[pp] * inv;
    }
}

// ---------------------------------------------------------------------------
// Gate GEMM: BM=128 BN=64 BK=64, pure global_load_lds staging, bias+relu,
// bf16 out. (Validated in R2/R3.)
// ---------------------------------------------------------------------------
template <int KIN, int NOUT>
__global__ __launch_bounds__(256, 2) void gemm_gate(const unsigned short* __restrict__ A,
                                                    const unsigned short* __restrict__ W,
                                                    const float* __restrict__ bias,
                                                    unsigned short* __restrict__ outb) {
    constexpr int BM = 128, BN = 64, BK = 64;

    __shared__ unsigned short sA[BM * BK];
    __shared__ unsigned short sB[BN * BK];

    const int t    = threadIdx.x;
    const int lane = t & 63;
    const int wid  = t >> 6;
    const int wm   = wid >> 1, wn = wid & 1;
    const int m0   = blockIdx.x * BM;
    const int n0   = blockIdx.y * BN;

    f32x4 acc[4][2];
#pragma unroll
    for (int i = 0; i < 4; ++i)
#pragma unroll
        for (int j = 0; j < 2; ++j) acc[i][j] = {0.f, 0.f, 0.f, 0.f};

#pragma unroll 1
    for (int kt = 0; kt < KIN / BK; ++kt) {
        const int ks = kt * BK;
        __syncthreads();
        const unsigned short* Wp = W + (size_t)n0 * KIN + ks;
#pragma unroll
        for (int c = 0; c < 2; ++c) {
            const int ch  = c * 256 + t;
            const int row = ch >> 3;
            const int gs  = (ch & 7) ^ (row & 7);
            __builtin_amdgcn_global_load_lds(
                (const __attribute__((address_space(1))) unsigned int*)(Wp + (size_t)row * KIN + gs * 8),
                (__attribute__((address_space(3))) unsigned int*)(sB + ch * 8), 16, 0, 0);
        }
        const unsigned short* Ap = A + (size_t)m0 * KIN + ks;
#pragma unroll
        for (int c = 0; c < 4; ++c) {
            const int ch  = c * 256 + t;
            const int row = ch >> 3;
            const int gs  = (ch & 7) ^ (row & 7);
            __builtin_amdgcn_global_load_lds(
                (const __attribute__((address_space(1))) unsigned int*)(Ap + (size_t)row * KIN + gs * 8),
                (__attribute__((address_space(3))) unsigned int*)(sA + ch * 8), 16, 0, 0);
        }
        __syncthreads();

#pragma unroll
        for (int kk = 0; kk < BK; kk += 32) {
            const int kb = kk + ((lane >> 4) << 3);
            s16x8 af[4], bfr[2];
#pragma unroll
            for (int mf = 0; mf < 4; ++mf) {
                const int row = wm * 64 + mf * 16 + (lane & 15);
                const int idx = (row * BK + kb) ^ ((row & 7) << 3);
                af[mf] = *(const s16x8*)(sA + idx);
            }
#pragma unroll
            for (int nf = 0; nf < 2; ++nf) {
                const int row = wn * 32 + nf * 16 + (lane & 15);
                const int idx = (row * BK + kb) ^ ((row & 7) << 3);
                bfr[nf] = *(const s16x8*)(sB + idx);
            }
#pragma unroll
            for (int mf = 0; mf < 4; ++mf)
#pragma unroll
                for (int nf = 0; nf < 2; ++nf)
                    acc[mf][nf] = __builtin_amdgcn_mfma_f32_16x16x32_bf16(af[mf], bfr[nf],
                                                                          acc[mf][nf], 0, 0, 0);
        }
    }

    const int cn = lane & 15;
    const int rb = (lane >> 4) << 2;
#pragma unroll
    for (int nf = 0; nf < 2; ++nf) {
        const int gn   = n0 + wn * 32 + nf * 16 + cn;
        const float bv = bias[gn];
#pragma unroll
        for (int mf = 0; mf < 4; ++mf) {
#pragma unroll
            for (int r = 0; r < 4; ++r) {
                const int gm = m0 + wm * 64 + mf * 16 + rb + r;
                float v = fmaxf(acc[mf][nf][r] + bv, 0.f);
                outb[(size_t)gm * NOUT + gn] = (unsigned short)(cvt_pk_bf16(v, v) & 0xffffu);
            }
        }
    }
}

// ---------------------------------------------------------------------------
// Expert GEMM, 8 waves (512 thr), wave grid 2x4, wave tile 64x32.
// Half-size accumulators (vs R3/R4's 64x64 wave tile) -> ~110 unified regs
// -> 4 waves/SIMD -> 2 resident 8-wave blocks/CU (16 waves) for latency
// hiding in the 2-barrier structure.
//   TPB = K-tiles/block; TPE = K-tiles/expert; NPE = experts per block.
//   NPE>1: dual-acc fold (mast += blend*eacc per expert).
//   NPE==1: single acc, scale by blend at partial write.
// ---------------------------------------------------------------------------
template <int KIN, int NOUT, int BN, int TPB>
__global__ __launch_bounds__(512, 2) void gemm_moe_sk8(const unsigned short* __restrict__ A,
                                                       const unsigned short* __restrict__ W,
                                                       const float* __restrict__ blend,
                                                       float* __restrict__ part) {
    constexpr int BM  = 128, BK = 64;
    constexpr int NF  = BN / 64;     // B fragments per wave (wave cols = BN/4)
    constexpr int TPE = KIN / BK;
    constexpr int NPE = (TPB >= TPE) ? TPB / TPE : 1;
    constexpr int ET  = (TPB >= TPE) ? TPE : TPB;
    static_assert((TPB % TPE == 0) || (TPE % TPB == 0), "split/expert alignment");

    __shared__ unsigned short sA[BM * BK];
    __shared__ unsigned short sB[BN * BK];

    const int t    = threadIdx.x;
    const int lane = t & 63;
    const int wid  = t >> 6;
    const int wm   = wid >> 2;       // 0..1  (64 rows each)
    const int wn   = wid & 3;        // 0..3  (BN/4 cols each)
    const int m0   = blockIdx.x * BM;
    const int n0   = blockIdx.y * BN;
    const int sp   = blockIdx.z;

    const int cn = lane & 15;
    const int rb = (lane >> 4) << 2;

    f32x4 mast[4][NF];
    if constexpr (NPE > 1) {
#pragma unroll
        for (int i = 0; i < 4; ++i)
#pragma unroll
            for (int j = 0; j < NF; ++j) mast[i][j] = {0.f, 0.f, 0.f, 0.f};
    }

    float lastbl[4];  // blend scale per mf-row (only used for NPE==1 path)

#pragma unroll 1
    for (int pe = 0; pe < NPE; ++pe) {
        const int tbase = sp * TPB + pe * ET;
        const int p     = tbase / TPE;
        const int ksb   = (tbase % TPE) * BK;

        f32x4 eacc[4][NF];
#pragma unroll
        for (int i = 0; i < 4; ++i)
#pragma unroll
            for (int j = 0; j < NF; ++j) eacc[i][j] = {0.f, 0.f, 0.f, 0.f};

        const unsigned short* Ap0 = A + (size_t)m0 * KIN + ksb;
        const unsigned short* Wp0 = W + ((size_t)p * NOUT + n0) * KIN + ksb;

#pragma unroll 1
        for (int kt = 0; kt < ET; ++kt) {
            const int ks = kt * BK;
            __syncthreads();
            // ---- B tile [BN][64] via global_load_lds (pre-swizzled source)
#pragma unroll
            for (int c = 0; c < BN * 8 / 512; ++c) {
                const int ch  = c * 512 + t;
                const int row = ch >> 3;
                const int gs  = (ch & 7) ^ (row & 7);
                __builtin_amdgcn_global_load_lds(
                    (const __attribute__((address_space(1))) unsigned int*)(Wp0 + (size_t)row * KIN + ks + gs * 8),
                    (__attribute__((address_space(3))) unsigned int*)(sB + ch * 8), 16, 0, 0);
            }
            // ---- A tile [128][64]
#pragma unroll
            for (int c = 0; c < 2; ++c) {
                const int ch  = c * 512 + t;
                const int row = ch >> 3;
                const int gs  = (ch & 7) ^ (row & 7);
                __builtin_amdgcn_global_load_lds(
                    (const __attribute__((address_space(1))) unsigned int*)(Ap0 + (size_t)row * KIN + ks + gs * 8),
                    (__attribute__((address_space(3))) unsigned int*)(sA + ch * 8), 16, 0, 0);
            }
            __syncthreads();

            // ---- compute: 2 K-steps of 32
#pragma unroll
            for (int kk = 0; kk < BK; kk += 32) {
                const int kb = kk + ((lane >> 4) << 3);
                s16x8 af[4], bfr[NF];
#pragma unroll
                for (int mf = 0; mf < 4; ++mf) {
                    const int row = wm * 64 + mf * 16 + (lane & 15);
                    const int idx = (row * BK + kb) ^ ((row & 7) << 3);
                    af[mf] = *(const s16x8*)(sA + idx);
                }
#pragma unroll
                for (int nf = 0; nf < NF; ++nf) {
                    const int row = wn * (BN / 4) + nf * 16 + (lane & 15);
                    const int idx = (row * BK + kb) ^ ((row & 7) << 3);
                    bfr[nf] = *(const s16x8*)(sB + idx);
                }
#pragma unroll
                for (int mf = 0; mf < 4; ++mf)
#pragma unroll
                    for (int nf = 0; nf < NF; ++nf)
                        eacc[mf][nf] = __builtin_amdgcn_mfma_f32_16x16x32_bf16(af[mf], bfr[nf],
                                                                               eacc[mf][nf], 0, 0, 0);
            }
        }

        // ---- fold expert-chunk
        if constexpr (NPE > 1) {
#pragma unroll
            for (int mf = 0; mf < 4; ++mf) {
#pragma unroll
                for (int r = 0; r < 4; ++r) {
                    const int gm = m0 + wm * 64 + mf * 16 + rb + r;
                    const float bl = blend[(size_t)gm * NEXPERT + p];
#pragma unroll
                    for (int nf = 0; nf < NF; ++nf)
                        mast[mf][nf][r] += bl * eacc[mf][nf][r];
                }
            }
        } else {
#pragma unroll
            for (int mf = 0; mf < 4; ++mf) {
                const int gm = m0 + wm * 64 + mf * 16 + rb;
                lastbl[mf] = 0.f;  // placeholder; per-r scale read below at write
                (void)gm;
#pragma unroll
                for (int r = 0; r < 4; ++r) {
                    const float bl = blend[(size_t)(m0 + wm * 64 + mf * 16 + rb + r) * NEXPERT + p];
#pragma unroll
                    for (int nf = 0; nf < NF; ++nf)
                        eacc[mf][nf][r] *= bl;
                }
#pragma unroll
                for (int nf = 0; nf < NF; ++nf) mast[mf][nf] = eacc[mf][nf];
            }
        }
    }
    (void)lastbl;

    // ---- write fp32 pre-blended partials. D: col = lane&15, row = 4*(lane>>4)+r
    float* dst = part + (size_t)sp * B_DIM * NOUT;
#pragma unroll
    for (int mf = 0; mf < 4; ++mf) {
#pragma unroll
        for (int r = 0; r < 4; ++r) {
            const int gm = m0 + wm * 64 + mf * 16 + rb + r;
#pragma unroll
            for (int nf = 0; nf < NF; ++nf) {
                const int gn = n0 + wn * (BN / 4) + nf * 16 + cn;
                dst[(size_t)gm * NOUT + gn] = mast[mf][nf][r];
            }
        }
    }
}

// ---------------------------------------------------------------------------
// Expert GEMM, 4 waves, wave grid 2x2 (R3 structure), for E2 (BN=64).
// NPE==1 specialization: single accumulator, blend-scale at partial write.
// ---------------------------------------------------------------------------
template <int KIN, int NOUT, int BN, int TPB>
__global__ __launch_bounds__(256, 2) void gemm_moe_sk4(const unsigned short* __restrict__ A,
                                                       const unsigned short* __restrict__ W,
                                                       const float* __restrict__ blend,
                                                       float* __restrict__ part) {
    constexpr int BM  = 128, BK = 64;
    constexpr int NF  = BN / 32;
    constexpr int TPE = KIN / BK;
    constexpr int NPE = (TPB >= TPE) ? TPB / TPE : 1;
    constexpr int ET  = (TPB >= TPE) ? TPE : TPB;
    static_assert((TPB % TPE == 0) || (TPE % TPB == 0), "split/expert alignment");
    static_assert(NPE == 1, "sk4 is the single-expert-chunk path");

    __shared__ unsigned short sA[BM * BK];
    __shared__ unsigned short sB[BN * BK];

    const int t    = threadIdx.x;
    const int lane = t & 63;
    const int wid  = t >> 6;
    const int wm   = wid >> 1, wn = wid & 1;
    const int m0   = blockIdx.x * BM;
    const int n0   = blockIdx.y * BN;
    const int sp   = blockIdx.z;

    const int cn = lane & 15;
    const int rb = (lane >> 4) << 2;

    const int tbase = sp * TPB;
    const int p     = tbase / TPE;
    const int ksb   = (tbase % TPE) * BK;

    f32x4 eacc[4][NF];
#pragma unroll
    for (int i = 0; i < 4; ++i)
#pragma unroll
        for (int j = 0; j < NF; ++j) eacc[i][j] = {0.f, 0.f, 0.f, 0.f};

    const unsigned short* Ap0 = A + (size_t)m0 * KIN + ksb;
    const unsigned short* Wp0 = W + ((size_t)p * NOUT + n0) * KIN + ksb;

#pragma unroll 1
    for (int kt = 0; kt < ET; ++kt) {
        const int ks = kt * BK;
        __syncthreads();
#pragma unroll
        for (int c = 0; c < NF; ++c) {
            const int ch  = c * 256 + t;
            const int row = ch >> 3;
            const int gs  = (ch & 7) ^ (row & 7);
            __builtin_amdgcn_global_load_lds(
                (const __attribute__((address_space(1))) unsigned int*)(Wp0 + (size_t)row * KIN + ks + gs * 8),
                (__attribute__((address_space(3))) unsigned int*)(sB + ch * 8), 16, 0, 0);
        }
#pragma unroll
        for (int c = 0; c < 4; ++c) {
            const int ch  = c * 256 + t;
            const int row = ch >> 3;
            const int gs  = (ch & 7) ^ (row & 7);
            __builtin_amdgcn_global_load_lds(
                (const __attribute__((address_space(1))) unsigned int*)(Ap0 + (size_t)row * KIN + ks + gs * 8),
                (__attribute__((address_space(3))) unsigned int*)(sA + ch * 8), 16, 0, 0);
        }
        __syncthreads();

#pragma unroll
        for (int kk = 0; kk < BK; kk += 32) {
            const int kb = kk + ((lane >> 4) << 3);
            s16x8 af[4], bfr[NF];
#pragma unroll
            for (int mf = 0; mf < 4; ++mf) {
                const int row = wm * 64 + mf * 16 + (lane & 15);
                const int idx = (row * BK + kb) ^ ((row & 7) << 3);
                af[mf] = *(const s16x8*)(sA + idx);
            }
#pragma unroll
            for (int nf = 0; nf < NF; ++nf) {
                const int row = wn * (BN / 2) + nf * 16 + (lane & 15);
                const int idx = (row * BK + kb) ^ ((row & 7) << 3);
                bfr[nf] = *(const s16x8*)(sB + idx);
            }
#pragma unroll
            for (int mf = 0; mf < 4; ++mf)
#pragma unroll
                for (int nf = 0; nf < NF; ++nf)
                    eacc[mf][nf] = __builtin_amdgcn_mfma_f32_16x16x32_bf16(af[mf], bfr[nf],
                                                                           eacc[mf][nf], 0, 0, 0);
        }
    }

    // blend-scale at write (single expert chunk)
    float* dst = part + (size_t)sp * B_DIM * NOUT;
#pragma unroll
    for (int mf = 0; mf < 4; ++mf) {
#pragma unroll
        for (int r = 0; r < 4; ++r) {
            const int gm = m0 + wm * 64 + mf * 16 + rb + r;
            const float bl = blend[(size_t)gm * NEXPERT + p];
#pragma unroll
            for (int nf = 0; nf < NF; ++nf) {
                const int gn = n0 + wn * (BN / 2) + nf * 16 + cn;
                dst[(size_t)gm * NOUT + gn] = bl * eacc[mf][nf][r];
            }
        }
    }
}

// ---------------------------------------------------------------------------
// Reduce NS fp32 partials + blended bias + relu -> bf16  (expert hidden)
// ---------------------------------------------------------------------------
template <int NS>
__global__ __launch_bounds__(256) void reduceN_relu(const float* __restrict__ part,
                                                    const float* __restrict__ blend,
                                                    const float* __restrict__ eb,
                                                    unsigned short* __restrict__ out) {
    const int tid = blockIdx.x * 256 + threadIdx.x;  // B*64 threads, 8 cols each
    const int row = tid >> 6;
    const int c0  = (tid & 63) << 3;

    float res[8] = {0.f, 0.f, 0.f, 0.f, 0.f, 0.f, 0.f, 0.f};
#pragma unroll
    for (int s = 0; s < NS; ++s) {
        const f32x4* ps = (const f32x4*)(part + ((size_t)s * B_DIM + row) * HID_DIM + c0);
        const f32x4 a = ps[0], b = ps[1];
#pragma unroll
        for (int j = 0; j < 4; ++j) { res[j] += a[j]; res[4 + j] += b[j]; }
    }
    const f32x4* bl = (const f32x4*)(blend + (size_t)row * NEXPERT);
    const f32x4 b0 = bl[0], b1 = bl[1];
    const float blv[8] = {b0[0], b0[1], b0[2], b0[3], b1[0], b1[1], b1[2], b1[3]};
#pragma unroll
    for (int pp = 0; pp < NEXPERT; ++pp) {
        const f32x4* e = (const f32x4*)(eb + (size_t)pp * HID_DIM + c0);
        const f32x4 e0 = e[0], e1 = e[1];
#pragma unroll
        for (int j = 0; j < 4; ++j) {
            res[j]     += blv[pp] * e0[j];
            res[4 + j] += blv[pp] * e1[j];
        }
    }
    u32x4 o;
#pragma unroll
    for (int j = 0; j < 4; ++j)
        o[j] = cvt_pk_bf16(fmaxf(res[2 * j], 0.f), fmaxf(res[2 * j + 1], 0.f));
    *(u32x4*)(out + (size_t)row * HID_DIM + c0) = o;
}

// ---------------------------------------------------------------------------
// Reduce 8 fp32 partials + blended bias + mu/std head -> f32  (final layer)
// ---------------------------------------------------------------------------
__global__ __launch_bounds__(256) void reduce8_head(const float* __restrict__ part,
                                                    const float* __restrict__ blend,
                                                    const float* __restrict__ eb2,
                                                    float* __restrict__ out) {
    const int tid = blockIdx.x * 256 + threadIdx.x;  // B*8 threads, 8 cols each
    const int row = tid >> 3;
    const int c0  = (tid & 7) << 3;

    float res[8] = {0.f, 0.f, 0.f, 0.f, 0.f, 0.f, 0.f, 0.f};
#pragma unroll
    for (int sp = 0; sp < 8; ++sp) {
        const f32x4* ps = (const f32x4*)(part + ((size_t)sp * B_DIM + row) * 64 + c0);
        const f32x4 a = ps[0], b = ps[1];
#pragma unroll
        for (int j = 0; j < 4; ++j) { res[j] += a[j]; res[4 + j] += b[j]; }
    }
    const f32x4* bl = (const f32x4*)(blend + (size_t)row * NEXPERT);
    const f32x4 b0 = bl[0], b1 = bl[1];
    const float blv[8] = {b0[0], b0[1], b0[2], b0[3], b1[0], b1[1], b1[2], b1[3]};
#pragma unroll
    for (int pp = 0; pp < NEXPERT; ++pp) {
        const f32x4* e = (const f32x4*)(eb2 + (size_t)pp * 64 + c0);
        const f32x4 e0 = e[0], e1 = e[1];
#pragma unroll
        for (int j = 0; j < 4; ++j) {
            res[j]     += blv[pp] * e0[j];
            res[4 + j] += blv[pp] * e1[j];
        }
    }
    f32x4 o0, o1;
#pragma unroll
    for (int j = 0; j < 8; ++j) {
        const int col = c0 + j;
        float v = res[j];
        if (col >= ACT_DIM) {
            const float vc = fminf(fmaxf(v, -15.f), 15.f);
            const float e2 = __expf(2.f * vc);
            const float th = (e2 - 1.f) / (e2 + 1.f);
            v = __expf(-1.5f + 3.5f * th);
        }
        if (j < 4) o0[j] = v; else o1[j - 4] = v;
    }
    f32x4* dst = (f32x4*)(out + (size_t)row * 64 + c0);
    dst[0] = o0;
    dst[1] = o1;
}

// ---------------------------------------------------------------------------
extern "C" void kernel_launch(void* const* d_in, const int* in_sizes, int n_in,
                              void* d_out, int out_size, void* d_ws, size_t ws_size,
                              hipStream_t stream) {
    const float* obs = (const float*)d_in[0];
    const float* gw0 = (const float*)d_in[1];
    const float* gb0 = (const float*)d_in[2];
    const float* gw1 = (const float*)d_in[3];
    const float* gb1 = (const float*)d_in[4];
    const float* gw2 = (const float*)d_in[5];
    const float* gb2 = (const float*)d_in[6];
    const float* ew0 = (const float*)d_in[7];
    const float* eb0 = (const float*)d_in[8];
    const float* ew1 = (const float*)d_in[9];
    const float* eb1 = (const float*)d_in[10];
    const float* ew2 = (const float*)d_in[11];
    const float* eb2 = (const float*)d_in[12];

    char* w = (char*)d_ws;
    auto alloc = [&](size_t bytes) {
        char* r = w;
        w += (bytes + 255) & ~(size_t)255;
        return r;
    };
    unsigned short* obs_bf = (unsigned short*)alloc((size_t)B_DIM * OBS_DIM * 2);
    unsigned short* gw0_bf = (unsigned short*)alloc((size_t)HID_DIM * OBS_DIM * 2);
    unsigned short* gw1_bf = (unsigned short*)alloc((size_t)HID_DIM * HID_DIM * 2);
    unsigned short* gw2_bf = (unsigned short*)alloc((size_t)NEXPERT * HID_DIM * 2);
    unsigned short* ew0_bf = (unsigned short*)alloc((size_t)NEXPERT * HID_DIM * OBS_DIM * 2);
    unsigned short* ew1_bf = (unsigned short*)alloc((size_t)NEXPERT * HID_DIM * HID_DIM * 2);
    unsigned short* ew2_bf = (unsigned short*)alloc((size_t)NEXPERT * 2 * ACT_DIM * HID_DIM * 2);
    unsigned short* h0     = (unsigned short*)alloc((size_t)B_DIM * HID_DIM * 2);
    unsigned short* h1     = (unsigned short*)alloc((size_t)B_DIM * HID_DIM * 2);
    float*          blend  = (float*)alloc((size_t)B_DIM * NEXPERT * 4);
    // 32 MB: covers split-2 x B x HID f32 partials, and E2's 8 x B x 64.
    float*          part   = (float*)alloc((size_t)2 * B_DIM * HID_DIM * 4);

    // convert all fp32 weights + obs to bf16 (one dispatch)
    CvtArgs ca;
    ca.s[0] = obs; ca.d[0] = obs_bf; ca.nb[0] = (B_DIM * OBS_DIM / 8) / 256;
    ca.s[1] = gw0; ca.d[1] = gw0_bf; ca.nb[1] = (HID_DIM * OBS_DIM / 8) / 256;
    ca.s[2] = gw1; ca.d[2] = gw1_bf; ca.nb[2] = (HID_DIM * HID_DIM / 8) / 256;
    ca.s[3] = gw2; ca.d[3] = gw2_bf; ca.nb[3] = (NEXPERT * HID_DIM / 8) / 256;
    ca.s[4] = ew0; ca.d[4] = ew0_bf; ca.nb[4] = (NEXPERT * HID_DIM * OBS_DIM / 8) / 256;
    ca.s[5] = ew1; ca.d[5] = ew1_bf; ca.nb[5] = (NEXPERT * HID_DIM * HID_DIM / 8) / 256;
    ca.s[6] = ew2; ca.d[6] = ew2_bf; ca.nb[6] = (NEXPERT * 64 * HID_DIM / 8) / 256;
    int total_blocks = 0;
    for (int i = 0; i < 7; ++i) total_blocks += ca.nb[i];
    cvt_multi<<<total_blocks, 256, 0, stream>>>(ca);

    // gate trunk
    gemm_gate<OBS_DIM, HID_DIM><<<dim3(B_DIM / 128, HID_DIM / 64), 256, 0, stream>>>(
        obs_bf, gw0_bf, gb0, h0);
    gemm_gate<HID_DIM, HID_DIM><<<dim3(B_DIM / 128, HID_DIM / 64), 256, 0, stream>>>(
        h0, gw1_bf, gb1, h1);
    gate_softmax<<<B_DIM / 4, 256, 0, stream>>>(h1, gw2_bf, gb2, blend);

    // E0: K=2048 (TPE=4), split 2 -> TPB=16 = 4 experts/block, 8-wave blocks
    gemm_moe_sk8<OBS_DIM, HID_DIM, 128, 16>
        <<<dim3(B_DIM / 128, HID_DIM / 128, 2), 512, 0, stream>>>(obs_bf, ew0_bf, blend, part);
    reduceN_relu<2><<<B_DIM * 64 / 256, 256, 0, stream>>>(part, blend, eb0, h0);

    // E1: K=4096 (TPE=8), split 2 -> TPB=32 = 4 experts/block, 8-wave blocks
    gemm_moe_sk8<HID_DIM, HID_DIM, 128, 32>
        <<<dim3(B_DIM / 128, HID_DIM / 128, 2), 512, 0, stream>>>(h0, ew1_bf, blend, part);
    reduceN_relu<2><<<B_DIM * 64 / 256, 256, 0, stream>>>(part, blend, eb1, h1);

    // E2: K=4096 (TPE=8), split 8 -> TPB=8 = exactly 1 expert/block, 4-wave
    gemm_moe_sk4<HID_DIM, 64, 64, 8>
        <<<dim3(B_DIM / 128, 1, 8), 256, 0, stream>>>(h1, ew2_bf, blend, part);
    reduce8_head<<<B_DIM * 8 / 256, 256, 0, stream>>>(part, blend, eb2, (float*)d_out);
}

// Round 6
// 209.756 us; speedup vs baseline: 1.1788x; 1.1788x over previous
//
#include <hip/hip_runtime.h>
#include <hip/hip_bf16.h>
#include <cstdint>
#include <cstddef>

// Problem constants
#define B_DIM   8192
#define OBS_DIM 256
#define ACT_DIM 32
#define HID_DIM 512
#define NEXPERT 8

typedef __attribute__((ext_vector_type(4))) float        f32x4;
typedef __attribute__((ext_vector_type(8))) short        s16x8;   // 8 bf16 in 4 VGPRs
typedef __attribute__((ext_vector_type(4))) unsigned int u32x4;

// v_cvt_pk_bf16_f32: D[15:0]=bf16(lo), D[31:16]=bf16(hi), RNE. No builtin on gfx950.
__device__ __forceinline__ unsigned cvt_pk_bf16(float lo, float hi) {
    unsigned r;
    asm("v_cvt_pk_bf16_f32 %0, %1, %2" : "=v"(r) : "v"(lo), "v"(hi));
    return r;
}
__device__ __forceinline__ float bf16_lo_f32(unsigned u) { return __uint_as_float(u << 16); }
__device__ __forceinline__ float bf16_hi_f32(unsigned u) { return __uint_as_float(u & 0xffff0000u); }

// ---------------------------------------------------------------------------
// fp32 -> bf16 bulk convert, 7 segments, block-partitioned.
// ---------------------------------------------------------------------------
struct CvtArgs {
    const float*    s[7];
    unsigned short* d[7];
    int             nb[7];
};

__global__ __launch_bounds__(256) void cvt_multi(CvtArgs a) {
    int bid = blockIdx.x;
    int seg = 0, base = 0;
    while (seg < 6 && bid >= base + a.nb[seg]) { base += a.nb[seg]; ++seg; }
    int local = (bid - base) * 256 + threadIdx.x;
    const f32x4* s = (const f32x4*)a.s[seg];
    f32x4 v0 = s[local * 2 + 0];
    f32x4 v1 = s[local * 2 + 1];
    u32x4 o;
    o[0] = cvt_pk_bf16(v0[0], v0[1]);
    o[1] = cvt_pk_bf16(v0[2], v0[3]);
    o[2] = cvt_pk_bf16(v1[0], v1[1]);
    o[3] = cvt_pk_bf16(v1[2], v1[3]);
    ((u32x4*)a.d[seg])[local] = o;
}

// ---------------------------------------------------------------------------
// Gate head: logits = h1 @ gw2.T + gb2 ; blend = softmax(logits). One wave/row.
// ---------------------------------------------------------------------------
__global__ __launch_bounds__(256) void gate_softmax(const unsigned short* __restrict__ h1,
                                                    const unsigned short* __restrict__ gw2,
                                                    const float* __restrict__ gb2,
                                                    float* __restrict__ blend) {
    const int lane = threadIdx.x & 63;
    const int wid  = threadIdx.x >> 6;
    const int row  = blockIdx.x * 4 + wid;

    u32x4 xv = *(const u32x4*)(h1 + (size_t)row * HID_DIM + lane * 8);
    float x[8];
#pragma unroll
    for (int j = 0; j < 4; ++j) {
        unsigned u   = xv[j];
        x[2 * j]     = bf16_lo_f32(u);
        x[2 * j + 1] = bf16_hi_f32(u);
    }
    float s[NEXPERT];
#pragma unroll
    for (int pp = 0; pp < NEXPERT; ++pp) {
        u32x4 wv = *(const u32x4*)(gw2 + (size_t)pp * HID_DIM + lane * 8);
        float d  = 0.f;
#pragma unroll
        for (int j = 0; j < 4; ++j) {
            unsigned u = wv[j];
            d += x[2 * j] * bf16_lo_f32(u);
            d += x[2 * j + 1] * bf16_hi_f32(u);
        }
        s[pp] = d;
    }
#pragma unroll
    for (int off = 1; off < 64; off <<= 1) {
#pragma unroll
        for (int pp = 0; pp < NEXPERT; ++pp) s[pp] += __shfl_xor(s[pp], off);
    }
    if (lane == 0) {
        float l[NEXPERT], m = -1e30f;
#pragma unroll
        for (int pp = 0; pp < NEXPERT; ++pp) { l[pp] = s[pp] + gb2[pp]; m = fmaxf(m, l[pp]); }
        float sum = 0.f;
#pragma unroll
        for (int pp = 0; pp < NEXPERT; ++pp) { l[pp] = __expf(l[pp] - m); sum += l[pp]; }
        float inv = 1.f / sum;
#pragma unroll
        for (int pp = 0; pp < NEXPERT; ++pp) blend[(size_t)row * NEXPERT + pp] = l[pp] * inv;
    }
}

// ---------------------------------------------------------------------------
// Gate GEMM, 2-phase prefetch: BM=128 BN=64 BK=64, double-buffered LDS,
// stage(t+1) issued BEFORE compute(t), ONE barrier per K-tile.
// bias+relu epilogue, bf16 out.
// ---------------------------------------------------------------------------
template <int KIN, int NOUT>
__global__ __launch_bounds__(256, 2) void gemm_gate(const unsigned short* __restrict__ A,
                                                    const unsigned short* __restrict__ W,
                                                    const float* __restrict__ bias,
                                                    unsigned short* __restrict__ outb) {
    constexpr int BM = 128, BN = 64, BK = 64;
    constexpr int NT = KIN / BK;

    __shared__ unsigned short sA[2][BM * BK]; // 2 x 16 KB
    __shared__ unsigned short sB[2][BN * BK]; // 2 x  8 KB

    const int t    = threadIdx.x;
    const int lane = t & 63;
    const int wid  = t >> 6;
    const int wm   = wid >> 1, wn = wid & 1;
    const int m0   = blockIdx.x * BM;
    const int n0   = blockIdx.y * BN;

    auto stage = [&](int tile, int buf) {
        const int ks = tile * BK;
        const unsigned short* Wp = W + (size_t)n0 * KIN + ks;
#pragma unroll
        for (int c = 0; c < 2; ++c) {
            const int ch  = c * 256 + t;
            const int row = ch >> 3;
            const int gs  = (ch & 7) ^ (row & 7);
            __builtin_amdgcn_global_load_lds(
                (const __attribute__((address_space(1))) unsigned int*)(Wp + (size_t)row * KIN + gs * 8),
                (__attribute__((address_space(3))) unsigned int*)(&sB[buf][ch * 8]), 16, 0, 0);
        }
        const unsigned short* Ap = A + (size_t)m0 * KIN + ks;
#pragma unroll
        for (int c = 0; c < 4; ++c) {
            const int ch  = c * 256 + t;
            const int row = ch >> 3;
            const int gs  = (ch & 7) ^ (row & 7);
            __builtin_amdgcn_global_load_lds(
                (const __attribute__((address_space(1))) unsigned int*)(Ap + (size_t)row * KIN + gs * 8),
                (__attribute__((address_space(3))) unsigned int*)(&sA[buf][ch * 8]), 16, 0, 0);
        }
    };

    f32x4 acc[4][2];
#pragma unroll
    for (int i = 0; i < 4; ++i)
#pragma unroll
        for (int j = 0; j < 2; ++j) acc[i][j] = {0.f, 0.f, 0.f, 0.f};

    stage(0, 0);
    __syncthreads();   // drains vmcnt(0) for buf0
    int cur = 0;

#pragma unroll 1
    for (int tile = 0; tile < NT; ++tile) {
        if (tile + 1 < NT) stage(tile + 1, cur ^ 1);  // loads fly during compute

#pragma unroll
        for (int kk = 0; kk < BK; kk += 32) {
            const int kb = kk + ((lane >> 4) << 3);
            s16x8 af[4], bfr[2];
#pragma unroll
            for (int mf = 0; mf < 4; ++mf) {
                const int row = wm * 64 + mf * 16 + (lane & 15);
                const int idx = (row * BK + kb) ^ ((row & 7) << 3);
                af[mf] = *(const s16x8*)(&sA[cur][idx]);
            }
#pragma unroll
            for (int nf = 0; nf < 2; ++nf) {
                const int row = wn * 32 + nf * 16 + (lane & 15);
                const int idx = (row * BK + kb) ^ ((row & 7) << 3);
                bfr[nf] = *(const s16x8*)(&sB[cur][idx]);
            }
#pragma unroll
            for (int mf = 0; mf < 4; ++mf)
#pragma unroll
                for (int nf = 0; nf < 2; ++nf)
                    acc[mf][nf] = __builtin_amdgcn_mfma_f32_16x16x32_bf16(af[mf], bfr[nf],
                                                                          acc[mf][nf], 0, 0, 0);
        }
        __syncthreads();  // next tile staged + this tile's reads done
        cur ^= 1;
    }

    const int cn = lane & 15;
    const int rb = (lane >> 4) << 2;
#pragma unroll
    for (int nf = 0; nf < 2; ++nf) {
        const int gn   = n0 + wn * 32 + nf * 16 + cn;
        const float bv = bias[gn];
#pragma unroll
        for (int mf = 0; mf < 4; ++mf) {
#pragma unroll
            for (int r = 0; r < 4; ++r) {
                const int gm = m0 + wm * 64 + mf * 16 + rb + r;
                float v = fmaxf(acc[mf][nf][r] + bv, 0.f);
                outb[(size_t)gm * NOUT + gn] = (unsigned short)(cvt_pk_bf16(v, v) & 0xffffu);
            }
        }
    }
}

// ---------------------------------------------------------------------------
// Expert GEMM, split-K, dual-accumulator blend fold, 2-phase prefetch.
// Flat K-tile loop over TPB tiles; expert index p = g/TPE; fold eacc->mast
// (mast += blend[b,p]*eacc, reg-only) whenever the expert boundary is crossed.
// Double-buffered LDS (64 KB at BN=128), stage(t+1) before compute(t),
// ONE barrier per K-tile. BM=128, 4 waves 2x2 (R3's proven shape).
// ---------------------------------------------------------------------------
template <int KIN, int NOUT, int BN, int TPB>
__global__ __launch_bounds__(256, 2) void gemm_moe_sk(const unsigned short* __restrict__ A,
                                                      const unsigned short* __restrict__ W,
                                                      const float* __restrict__ blend,
                                                      float* __restrict__ part) {
    constexpr int BM  = 128, BK = 64;
    constexpr int NF  = BN / 32;     // B fragments per wave (waves 2x2)
    constexpr int TPE = KIN / BK;    // K-tiles per expert (power of 2)
    constexpr int ET  = (TPB >= TPE) ? TPE : TPB;  // tiles per expert-chunk
    static_assert((TPB % TPE == 0) || (TPE % TPB == 0), "split/expert alignment");

    __shared__ unsigned short sA[2][BM * BK];
    __shared__ unsigned short sB[2][BN * BK];

    const int t    = threadIdx.x;
    const int lane = t & 63;
    const int wid  = t >> 6;
    const int wm   = wid >> 1, wn = wid & 1;
    const int m0   = blockIdx.x * BM;
    const int n0   = blockIdx.y * BN;
    const int sp   = blockIdx.z;

    const int cn = lane & 15;
    const int rb = (lane >> 4) << 2;
    const unsigned gbase = (unsigned)sp * TPB;

    auto stage = [&](int tile, int buf) {
        const unsigned g  = gbase + (unsigned)tile;
        const unsigned p  = g / TPE;          // expert (shift; TPE pow2)
        const unsigned ko = (g % TPE) * BK;   // K-offset within expert
        const unsigned short* Wp = W + ((size_t)p * NOUT + n0) * KIN + ko;
#pragma unroll
        for (int c = 0; c < BN / 32; ++c) {
            const int ch  = c * 256 + t;
            const int row = ch >> 3;
            const int gs  = (ch & 7) ^ (row & 7);
            __builtin_amdgcn_global_load_lds(
                (const __attribute__((address_space(1))) unsigned int*)(Wp + (size_t)row * KIN + gs * 8),
                (__attribute__((address_space(3))) unsigned int*)(&sB[buf][ch * 8]), 16, 0, 0);
        }
        const unsigned short* Ap = A + (size_t)m0 * KIN + ko;
#pragma unroll
        for (int c = 0; c < 4; ++c) {
            const int ch  = c * 256 + t;
            const int row = ch >> 3;
            const int gs  = (ch & 7) ^ (row & 7);
            __builtin_amdgcn_global_load_lds(
                (const __attribute__((address_space(1))) unsigned int*)(Ap + (size_t)row * KIN + gs * 8),
                (__attribute__((address_space(3))) unsigned int*)(&sA[buf][ch * 8]), 16, 0, 0);
        }
    };

    f32x4 mast[4][NF], eacc[4][NF];
#pragma unroll
    for (int i = 0; i < 4; ++i)
#pragma unroll
        for (int j = 0; j < NF; ++j) {
            mast[i][j] = {0.f, 0.f, 0.f, 0.f};
            eacc[i][j] = {0.f, 0.f, 0.f, 0.f};
        }

    stage(0, 0);
    __syncthreads();
    int cur = 0;

#pragma unroll 1
    for (int tile = 0; tile < TPB; ++tile) {
        if (tile + 1 < TPB) stage(tile + 1, cur ^ 1);

        // ---- compute tile from buf[cur]: 2 K-steps of 32
#pragma unroll
        for (int kk = 0; kk < BK; kk += 32) {
            const int kb = kk + ((lane >> 4) << 3);
            s16x8 af[4], bfr[NF];
#pragma unroll
            for (int mf = 0; mf < 4; ++mf) {
                const int row = wm * 64 + mf * 16 + (lane & 15);
                const int idx = (row * BK + kb) ^ ((row & 7) << 3);
                af[mf] = *(const s16x8*)(&sA[cur][idx]);
            }
#pragma unroll
            for (int nf = 0; nf < NF; ++nf) {
                const int row = wn * (BN / 2) + nf * 16 + (lane & 15);
                const int idx = (row * BK + kb) ^ ((row & 7) << 3);
                bfr[nf] = *(const s16x8*)(&sB[cur][idx]);
            }
#pragma unroll
            for (int mf = 0; mf < 4; ++mf)
#pragma unroll
                for (int nf = 0; nf < NF; ++nf)
                    eacc[mf][nf] = __builtin_amdgcn_mfma_f32_16x16x32_bf16(af[mf], bfr[nf],
                                                                           eacc[mf][nf], 0, 0, 0);
        }

        // ---- expert boundary: fold eacc into master (reg-only + blend loads)
        if (((tile + 1) & (ET - 1)) == 0) {
            const unsigned p = (gbase + (unsigned)tile) / TPE;
#pragma unroll
            for (int mf = 0; mf < 4; ++mf) {
#pragma unroll
                for (int r = 0; r < 4; ++r) {
                    const int gm = m0 + wm * 64 + mf * 16 + rb + r;
                    const float bl = blend[(size_t)gm * NEXPERT + p];
#pragma unroll
                    for (int nf = 0; nf < NF; ++nf) {
                        mast[mf][nf][r] += bl * eacc[mf][nf][r];
                        eacc[mf][nf][r] = 0.f;
                    }
                }
            }
        }

        __syncthreads();
        cur ^= 1;
    }

    // ---- write fp32 pre-blended partials. D: col = lane&15, row = 4*(lane>>4)+r
    float* dst = part + (size_t)sp * B_DIM * NOUT;
#pragma unroll
    for (int mf = 0; mf < 4; ++mf) {
#pragma unroll
        for (int r = 0; r < 4; ++r) {
            const int gm = m0 + wm * 64 + mf * 16 + rb + r;
#pragma unroll
            for (int nf = 0; nf < NF; ++nf) {
                const int gn = n0 + wn * (BN / 2) + nf * 16 + cn;
                dst[(size_t)gm * NOUT + gn] = mast[mf][nf][r];
            }
        }
    }
}

// ---------------------------------------------------------------------------
// Reduce NS fp32 partials + blended bias + relu -> bf16  (expert hidden)
// ---------------------------------------------------------------------------
template <int NS>
__global__ __launch_bounds__(256) void reduceN_relu(const float* __restrict__ part,
                                                    const float* __restrict__ blend,
                                                    const float* __restrict__ eb,
                                                    unsigned short* __restrict__ out) {
    const int tid = blockIdx.x * 256 + threadIdx.x;  // B*64 threads, 8 cols each
    const int row = tid >> 6;
    const int c0  = (tid & 63) << 3;

    float res[8] = {0.f, 0.f, 0.f, 0.f, 0.f, 0.f, 0.f, 0.f};
#pragma unroll
    for (int s = 0; s < NS; ++s) {
        const f32x4* ps = (const f32x4*)(part + ((size_t)s * B_DIM + row) * HID_DIM + c0);
        const f32x4 a = ps[0], b = ps[1];
#pragma unroll
        for (int j = 0; j < 4; ++j) { res[j] += a[j]; res[4 + j] += b[j]; }
    }
    const f32x4* bl = (const f32x4*)(blend + (size_t)row * NEXPERT);
    const f32x4 b0 = bl[0], b1 = bl[1];
    const float blv[8] = {b0[0], b0[1], b0[2], b0[3], b1[0], b1[1], b1[2], b1[3]};
#pragma unroll
    for (int pp = 0; pp < NEXPERT; ++pp) {
        const f32x4* e = (const f32x4*)(eb + (size_t)pp * HID_DIM + c0);
        const f32x4 e0 = e[0], e1 = e[1];
#pragma unroll
        for (int j = 0; j < 4; ++j) {
            res[j]     += blv[pp] * e0[j];
            res[4 + j] += blv[pp] * e1[j];
        }
    }
    u32x4 o;
#pragma unroll
    for (int j = 0; j < 4; ++j)
        o[j] = cvt_pk_bf16(fmaxf(res[2 * j], 0.f), fmaxf(res[2 * j + 1], 0.f));
    *(u32x4*)(out + (size_t)row * HID_DIM + c0) = o;
}

// ---------------------------------------------------------------------------
// Reduce 8 fp32 partials + blended bias + mu/std head -> f32  (final layer)
// ---------------------------------------------------------------------------
__global__ __launch_bounds__(256) void reduce8_head(const float* __restrict__ part,
                                                    const float* __restrict__ blend,
                                                    const float* __restrict__ eb2,
                                                    float* __restrict__ out) {
    const int tid = blockIdx.x * 256 + threadIdx.x;  // B*8 threads, 8 cols each
    const int row = tid >> 3;
    const int c0  = (tid & 7) << 3;

    float res[8] = {0.f, 0.f, 0.f, 0.f, 0.f, 0.f, 0.f, 0.f};
#pragma unroll
    for (int sp = 0; sp < 8; ++sp) {
        const f32x4* ps = (const f32x4*)(part + ((size_t)sp * B_DIM + row) * 64 + c0);
        const f32x4 a = ps[0], b = ps[1];
#pragma unroll
        for (int j = 0; j < 4; ++j) { res[j] += a[j]; res[4 + j] += b[j]; }
    }
    const f32x4* bl = (const f32x4*)(blend + (size_t)row * NEXPERT);
    const f32x4 b0 = bl[0], b1 = bl[1];
    const float blv[8] = {b0[0], b0[1], b0[2], b0[3], b1[0], b1[1], b1[2], b1[3]};
#pragma unroll
    for (int pp = 0; pp < NEXPERT; ++pp) {
        const f32x4* e = (const f32x4*)(eb2 + (size_t)pp * 64 + c0);
        const f32x4 e0 = e[0], e1 = e[1];
#pragma unroll
        for (int j = 0; j < 4; ++j) {
            res[j]     += blv[pp] * e0[j];
            res[4 + j] += blv[pp] * e1[j];
        }
    }
    f32x4 o0, o1;
#pragma unroll
    for (int j = 0; j < 8; ++j) {
        const int col = c0 + j;
        float v = res[j];
        if (col >= ACT_DIM) {
            const float vc = fminf(fmaxf(v, -15.f), 15.f);
            const float e2 = __expf(2.f * vc);
            const float th = (e2 - 1.f) / (e2 + 1.f);
            v = __expf(-1.5f + 3.5f * th);
        }
        if (j < 4) o0[j] = v; else o1[j - 4] = v;
    }
    f32x4* dst = (f32x4*)(out + (size_t)row * 64 + c0);
    dst[0] = o0;
    dst[1] = o1;
}

// ---------------------------------------------------------------------------
extern "C" void kernel_launch(void* const* d_in, const int* in_sizes, int n_in,
                              void* d_out, int out_size, void* d_ws, size_t ws_size,
                              hipStream_t stream) {
    const float* obs = (const float*)d_in[0];
    const float* gw0 = (const float*)d_in[1];
    const float* gb0 = (const float*)d_in[2];
    const float* gw1 = (const float*)d_in[3];
    const float* gb1 = (const float*)d_in[4];
    const float* gw2 = (const float*)d_in[5];
    const float* gb2 = (const float*)d_in[6];
    const float* ew0 = (const float*)d_in[7];
    const float* eb0 = (const float*)d_in[8];
    const float* ew1 = (const float*)d_in[9];
    const float* eb1 = (const float*)d_in[10];
    const float* ew2 = (const float*)d_in[11];
    const float* eb2 = (const float*)d_in[12];

    char* w = (char*)d_ws;
    auto alloc = [&](size_t bytes) {
        char* r = w;
        w += (bytes + 255) & ~(size_t)255;
        return r;
    };
    unsigned short* obs_bf = (unsigned short*)alloc((size_t)B_DIM * OBS_DIM * 2);
    unsigned short* gw0_bf = (unsigned short*)alloc((size_t)HID_DIM * OBS_DIM * 2);
    unsigned short* gw1_bf = (unsigned short*)alloc((size_t)HID_DIM * HID_DIM * 2);
    unsigned short* gw2_bf = (unsigned short*)alloc((size_t)NEXPERT * HID_DIM * 2);
    unsigned short* ew0_bf = (unsigned short*)alloc((size_t)NEXPERT * HID_DIM * OBS_DIM * 2);
    unsigned short* ew1_bf = (unsigned short*)alloc((size_t)NEXPERT * HID_DIM * HID_DIM * 2);
    unsigned short* ew2_bf = (unsigned short*)alloc((size_t)NEXPERT * 2 * ACT_DIM * HID_DIM * 2);
    unsigned short* h0     = (unsigned short*)alloc((size_t)B_DIM * HID_DIM * 2);
    unsigned short* h1     = (unsigned short*)alloc((size_t)B_DIM * HID_DIM * 2);
    float*          blend  = (float*)alloc((size_t)B_DIM * NEXPERT * 4);
    // 32 MB: covers split-2 x B x HID f32 partials, and E2's 8 x B x 64.
    float*          part   = (float*)alloc((size_t)2 * B_DIM * HID_DIM * 4);

    // convert all fp32 weights + obs to bf16 (one dispatch)
    CvtArgs ca;
    ca.s[0] = obs; ca.d[0] = obs_bf; ca.nb[0] = (B_DIM * OBS_DIM / 8) / 256;
    ca.s[1] = gw0; ca.d[1] = gw0_bf; ca.nb[1] = (HID_DIM * OBS_DIM / 8) / 256;
    ca.s[2] = gw1; ca.d[2] = gw1_bf; ca.nb[2] = (HID_DIM * HID_DIM / 8) / 256;
    ca.s[3] = gw2; ca.d[3] = gw2_bf; ca.nb[3] = (NEXPERT * HID_DIM / 8) / 256;
    ca.s[4] = ew0; ca.d[4] = ew0_bf; ca.nb[4] = (NEXPERT * HID_DIM * OBS_DIM / 8) / 256;
    ca.s[5] = ew1; ca.d[5] = ew1_bf; ca.nb[5] = (NEXPERT * HID_DIM * HID_DIM / 8) / 256;
    ca.s[6] = ew2; ca.d[6] = ew2_bf; ca.nb[6] = (NEXPERT * 64 * HID_DIM / 8) / 256;
    int total_blocks = 0;
    for (int i = 0; i < 7; ++i) total_blocks += ca.nb[i];
    cvt_multi<<<total_blocks, 256, 0, stream>>>(ca);

    // gate trunk
    gemm_gate<OBS_DIM, HID_DIM><<<dim3(B_DIM / 128, HID_DIM / 64), 256, 0, stream>>>(
        obs_bf, gw0_bf, gb0, h0);
    gemm_gate<HID_DIM, HID_DIM><<<dim3(B_DIM / 128, HID_DIM / 64), 256, 0, stream>>>(
        h0, gw1_bf, gb1, h1);
    gate_softmax<<<B_DIM / 4, 256, 0, stream>>>(h1, gw2_bf, gb2, blend);

    // E0: K=2048 (TPE=4), split 2 -> TPB=16 = 4 experts/block, grid (64,4,2)
    gemm_moe_sk<OBS_DIM, HID_DIM, 128, 16>
        <<<dim3(B_DIM / 128, HID_DIM / 128, 2), 256, 0, stream>>>(obs_bf, ew0_bf, blend, part);
    reduceN_relu<2><<<B_DIM * 64 / 256, 256, 0, stream>>>(part, blend, eb0, h0);

    // E1: K=4096 (TPE=8), split 2 -> TPB=32 = 4 experts/block, grid (64,4,2)
    gemm_moe_sk<HID_DIM, HID_DIM, 128, 32>
        <<<dim3(B_DIM / 128, HID_DIM / 128, 2), 256, 0, stream>>>(h0, ew1_bf, blend, part);
    reduceN_relu<2><<<B_DIM * 64 / 256, 256, 0, stream>>>(part, blend, eb1, h1);

    // E2: K=4096 (TPE=8), split 8 -> TPB=8 = 1 expert/block, fold fires once
    gemm_moe_sk<HID_DIM, 64, 64, 8>
        <<<dim3(B_DIM / 128, 1, 8), 256, 0, stream>>>(h1, ew2_bf, blend, part);
    reduce8_head<<<B_DIM * 8 / 256, 256, 0, stream>>>(part, blend, eb2, (float*)d_out);
}